// Round 9
// baseline (172.553 us; speedup 1.0000x reference)
//
#include <hip/hip_runtime.h>
#include <math.h>

namespace {

constexpr int B   = 2048;
constexpr int L   = 200;
constexpr int E   = 96;    // 3 * D_FEAT
constexpr int U   = 64;
constexpr int NA  = 36;    // HID_ATT
constexpr int H1  = 200;
constexpr int H2  = 80;
constexpr int RB  = 8;     // rows per block for gemm1/mlp/final
constexpr int NBLK = B / RB;   // 256

__device__ __forceinline__ float sigf(float x) {
    return 1.0f / (1.0f + __expf(-x));
}

// VALU-only partial reduce: 4 DPP adds + one shfl_xor(16).
template <int CTRL>
__device__ __forceinline__ float dppadd(float x) {
    int v = __builtin_amdgcn_update_dpp(0, __builtin_bit_cast(int, x),
                                        CTRL, 0xf, 0xf, true);
    return x + __builtin_bit_cast(float, v);
}
__device__ __forceinline__ float grp32_sum(float p) {
    p = dppadd<0xB1>(p);    // lane ^ 1
    p = dppadd<0x4E>(p);    // lane ^ 2
    p = dppadd<0x141>(p);   // row_half_mirror (^7)
    p = dppadd<0x140>(p);   // row_mirror (^15)
    p += __shfl_xor(p, 16);
    return p;
}

// ---------------------------------------------------------------------------
// K1: one batch row per block. Per-block fold of the linear attention MLP,
// then 8 groups x 32 lanes x 25 items of fused score+browse.
// Block 0 also zeroes the two done-counters for the last-block stats.
// ---------------------------------------------------------------------------
__global__ __launch_bounds__(256) void k_attn(
    const int* __restrict__ user, const int* __restrict__ item,
    const int* __restrict__ rec,
    const float* __restrict__ tu, const float* __restrict__ t1,
    const float* __restrict__ t2, const float* __restrict__ t3,
    const float* __restrict__ w_att1, const float* __restrict__ b_att1,
    const float* __restrict__ w_att2, const float* __restrict__ b_att2,
    float* __restrict__ feat, int* __restrict__ ctrs)
{
    __shared__ float s_v[292];
    __shared__ __align__(16) float s_feat[256];
    __shared__ float s_part[8][E];
    __shared__ __align__(16) int4 s_idx4[L];

    const int b = blockIdx.x, t = threadIdx.x;
    const int g = t >> 5, lane = t & 31;

    if (b == 0 && t < 2) ctrs[t] = 0;     // reset last-block counters each call

    // ---- fold: s_v[0..95]=v1+v3 | [96..191]=v2-v3 | [192..287]=v4 | [288]=c
    for (int j = t; j < 289; j += 256) {
        float s;
        if (j < 96) {
            s = 0.f;
            #pragma unroll
            for (int k = 0; k < NA; ++k)
                s += w_att2[k] * (w_att1[k * 384 + j] + w_att1[k * 384 + 192 + j]);
        } else if (j < 192) {
            const int e = j - 96; s = 0.f;
            #pragma unroll
            for (int k = 0; k < NA; ++k)
                s += w_att2[k] * (w_att1[k * 384 + 96 + e] - w_att1[k * 384 + 192 + e]);
        } else if (j < 288) {
            const int e = j - 192; s = 0.f;
            #pragma unroll
            for (int k = 0; k < NA; ++k)
                s += w_att2[k] * w_att1[k * 384 + 288 + e];
        } else {
            s = b_att2[0];
            #pragma unroll
            for (int k = 0; k < NA; ++k) s += w_att2[k] * b_att1[k];
        }
        s_v[j] = s;
    }

    // ---- stage idx (padded to int4), q, user emb ---------------------------
    {
        int* si = (int*)s_idx4;
        for (int i = t; i < L * 3; i += 256) {
            const int v = rec[(size_t)b * L * 3 + i];
            si[(i / 3) * 4 + (i % 3)] = v;
        }
    }
    if (t < E) {                          // q = item_emb -> feat[0..95]
        const int f = t >> 5, e = t & 31;
        const float* tab = (f == 0) ? t1 : ((f == 1) ? t2 : t3);
        s_feat[t] = tab[item[b * 3 + f] * 32 + e];
    }
    if (t >= 192) s_feat[t] = tu[(size_t)user[b] * U + (t - 192)];
    __syncthreads();

    const float q0 = s_feat[lane], q1 = s_feat[32 + lane], q2 = s_feat[64 + lane];
    const float wa = s_v[96 + lane]  + q0 * s_v[192 + lane];
    const float wb = s_v[128 + lane] + q1 * s_v[224 + lane];
    const float wc = s_v[160 + lane] + q2 * s_v[256 + lane];
    float cb = q0 * s_v[lane] + q1 * s_v[32 + lane] + q2 * s_v[64 + lane];
    cb = grp32_sum(cb) + s_v[288];

    float a0 = 0.f, a1v = 0.f, a2v = 0.f;
    #pragma unroll 5
    for (int i = 0; i < 25; ++i) {
        const int4 iv = s_idx4[g * 25 + i];
        const float u0 = t1[iv.x * 32 + lane];
        const float u1 = t2[iv.y * 32 + lane];
        const float u2 = t3[iv.z * 32 + lane];
        float p = u0 * wa + u1 * wb + u2 * wc;
        p = grp32_sum(p);
        const float sc = (iv.x == 0) ? 0.f : (cb + p);
        a0 += sc * u0; a1v += sc * u1; a2v += sc * u2;
    }
    s_part[g][lane]      = a0;
    s_part[g][32 + lane] = a1v;
    s_part[g][64 + lane] = a2v;
    __syncthreads();

    if (t < E) {
        float s = 0.f;
        #pragma unroll
        for (int gg = 0; gg < 8; ++gg) s += s_part[gg][t];
        s_feat[96 + t] = s;
    }
    __syncthreads();

    feat[(size_t)b * 256 + t] = s_feat[t];
}

// ---------------------------------------------------------------------------
// Last-block column-stats reduce: partsT is [2*NCOL][NBLK]; the last block to
// finish reduces every 256-wide row with wave64 float4 reads + DPP tree and
// writes sc/sh. Deterministic: fixed reduction order, one executor.
// ---------------------------------------------------------------------------
template <int NCOL>
__device__ __forceinline__ void lastblock_stats(
    const float* __restrict__ partsT, const float* __restrict__ g,
    const float* __restrict__ be, float* __restrict__ sc,
    float* __restrict__ sh, int* __restrict__ ctr,
    float* __restrict__ colred /* LDS [2*NCOL] */, int t)
{
    __shared__ int s_last;
    __threadfence();
    __syncthreads();
    if (t == 0) s_last = (atomicAdd(ctr, 1) == NBLK - 1) ? 1 : 0;
    __syncthreads();
    if (!s_last) return;
    __threadfence();

    const int wv = t >> 6, ln = t & 63;
    for (int row = wv; row < 2 * NCOL; row += 4) {
        const float4 v = ((const float4*)(partsT + (size_t)row * NBLK))[ln];
        float s = (v.x + v.y) + (v.z + v.w);
        s = grp32_sum(s);
        s += __shfl_xor(s, 32);
        if (ln == 0) colred[row] = s;
    }
    __syncthreads();
    if (t < NCOL) {
        const float mean = colred[t] * (1.f / B);
        float var = (colred[NCOL + t] - (float)B * mean * mean) * (1.f / (B - 1));
        var = fmaxf(var, 0.f);
        const float a = g[t] * rsqrtf(var + 1e-8f);
        sc[t] = a;
        sh[t] = be[t] - mean * a;
    }
}

// ---------------------------------------------------------------------------
// K2: y1 = feat @ w1^T + b1 (8 rows/block); transposed column partials; the
// last block finalizes dice-1 scale/shift in-kernel.
// ---------------------------------------------------------------------------
__global__ __launch_bounds__(256) void k_gemm1(
    const float* __restrict__ feat,
    const float* __restrict__ w1, const float* __restrict__ b1,
    const float* __restrict__ g1, const float* __restrict__ be1,
    float* __restrict__ y1, float* __restrict__ part1t,
    float* __restrict__ sc1, float* __restrict__ sh1, int* __restrict__ ctr)
{
    __shared__ __align__(16) float s_f[RB * 256];
    __shared__ float s_red[2 * H1];
    const int t = threadIdx.x, b0 = blockIdx.x * RB;

    const float4* src = (const float4*)(feat + (size_t)b0 * 256);
    float4* dst = (float4*)s_f;
    dst[t] = src[t];
    dst[t + 256] = src[t + 256];
    __syncthreads();

    if (t < H1) {
        const float4* wr = (const float4*)(w1 + t * 256);
        float acc[RB];
        const float bj = b1[t];
        #pragma unroll
        for (int bb = 0; bb < RB; ++bb) acc[bb] = bj;
        #pragma unroll 4
        for (int k = 0; k < 64; ++k) {
            const float4 w = wr[k];
            #pragma unroll
            for (int bb = 0; bb < RB; ++bb) {
                const float4 f = ((const float4*)(s_f + bb * 256))[k];
                acc[bb] += w.x * f.x + w.y * f.y + w.z * f.z + w.w * f.w;
            }
        }
        float s1 = 0.f, s2 = 0.f;
        #pragma unroll
        for (int bb = 0; bb < RB; ++bb) {
            y1[(size_t)(b0 + bb) * H1 + t] = acc[bb];
            s1 += acc[bb]; s2 += acc[bb] * acc[bb];
        }
        part1t[(size_t)t * NBLK + blockIdx.x]        = s1;
        part1t[(size_t)(H1 + t) * NBLK + blockIdx.x] = s2;
    }

    lastblock_stats<H1>(part1t, g1, be1, sc1, sh1, ctr, s_red, t);
}

// ---------------------------------------------------------------------------
// K3: dice(y1) -> y2 = x @ w2^T + b2 (8 rows/block); transposed partials;
// last block finalizes dice-2 scale/shift.
// ---------------------------------------------------------------------------
__global__ __launch_bounds__(256) void k_mlp(
    const float* __restrict__ y1,
    const float* __restrict__ sc1, const float* __restrict__ sh1,
    const float* __restrict__ a1,
    const float* __restrict__ w2, const float* __restrict__ b2,
    const float* __restrict__ g2, const float* __restrict__ be2,
    float* __restrict__ y2, float* __restrict__ part2t,
    float* __restrict__ sc2, float* __restrict__ sh2, int* __restrict__ ctr)
{
    __shared__ float s_c1[H1], s_h1[H1], s_al[H1];
    __shared__ __align__(16) float s_x[RB][H1];
    __shared__ float s_p1[3][H2], s_p2[3][H2];
    __shared__ float s_red[2 * H2];
    const int t = threadIdx.x, b0 = blockIdx.x * RB;

    if (t < H1) { s_c1[t] = sc1[t]; s_h1[t] = sh1[t]; s_al[t] = a1[t]; }
    __syncthreads();

    for (int i = t; i < RB * H1; i += 256) {
        const int j = i % H1;
        const float xn = y1[(size_t)b0 * H1 + i] * s_c1[j] + s_h1[j];
        const float p  = sigf(xn);
        s_x[i / H1][j] = xn * (p + s_al[j] * (1.f - p));
    }
    __syncthreads();

    const int j = t % H2, rg = t / H2;    // rg 0..2 for t<240
    if (t < 240) {
        const int base = rg * 3;
        const int nb = (rg < 2) ? 3 : 2;  // rows 3/3/2 = 8
        const float4* wr = (const float4*)(w2 + j * H1);
        float acc[3];
        const float bj = b2[j];
        #pragma unroll
        for (int r = 0; r < 3; ++r) acc[r] = bj;
        #pragma unroll 2
        for (int k = 0; k < H1 / 4; ++k) {
            const float4 w = wr[k];
            for (int r = 0; r < nb; ++r) {
                const float4 x = ((const float4*)s_x[base + r])[k];
                acc[r] += w.x * x.x + w.y * x.y + w.z * x.z + w.w * x.w;
            }
        }
        float s1 = 0.f, s2 = 0.f;
        for (int r = 0; r < nb; ++r) {
            y2[(size_t)(b0 + base + r) * H2 + j] = acc[r];
            s1 += acc[r]; s2 += acc[r] * acc[r];
        }
        s_p1[rg][j] = s1; s_p2[rg][j] = s2;
    }
    __syncthreads();
    if (t < H2) {
        part2t[(size_t)t * NBLK + blockIdx.x]        = s_p1[0][t] + s_p1[1][t] + s_p1[2][t];
        part2t[(size_t)(H2 + t) * NBLK + blockIdx.x] = s_p2[0][t] + s_p2[1][t] + s_p2[2][t];
    }

    lastblock_stats<H2>(part2t, g2, be2, sc2, sh2, ctr, s_red, t);
}

// ---------------------------------------------------------------------------
// K4: dice(y2), dot w3, sigmoid. 8 rows/block, 32 lanes per row.
// ---------------------------------------------------------------------------
__global__ __launch_bounds__(256) void k_final(
    const float* __restrict__ y2,
    const float* __restrict__ sc2, const float* __restrict__ sh2,
    const float* __restrict__ a2,
    const float* __restrict__ w3, const float* __restrict__ b3,
    float* __restrict__ out)
{
    __shared__ float s_c[H2], s_s[H2], s_aw[H2], s_w3[H2];
    const int t = threadIdx.x, b0 = blockIdx.x * RB;
    const int g = t >> 5, lane = t & 31;

    if (t < H2) {
        s_c[t] = sc2[t]; s_s[t] = sh2[t];
        s_aw[t] = a2[t]; s_w3[t] = w3[t];
    }
    __syncthreads();

    const int r = b0 + g;
    float acc = 0.f;
    #pragma unroll
    for (int jj = 0; jj < 3; ++jj) {
        const int j = lane + jj * 32;
        if (j < H2) {
            const float xn = y2[(size_t)r * H2 + j] * s_c[j] + s_s[j];
            const float p  = sigf(xn);
            acc += xn * (p + s_aw[j] * (1.f - p)) * s_w3[j];
        }
    }
    acc = grp32_sum(acc);
    if (lane == 0) out[r] = sigf(acc + b3[0]);
}

} // namespace

extern "C" void kernel_launch(void* const* d_in, const int* in_sizes, int n_in,
                              void* d_out, int out_size, void* d_ws, size_t ws_size,
                              hipStream_t stream) {
    const int*   user   = (const int*)d_in[0];
    const int*   item   = (const int*)d_in[1];
    const int*   rec    = (const int*)d_in[2];
    const float* tu     = (const float*)d_in[3];
    const float* t1     = (const float*)d_in[4];
    const float* t2     = (const float*)d_in[5];
    const float* t3     = (const float*)d_in[6];
    const float* w_att1 = (const float*)d_in[7];
    const float* b_att1 = (const float*)d_in[8];
    const float* w_att2 = (const float*)d_in[9];
    const float* b_att2 = (const float*)d_in[10];
    const float* w1     = (const float*)d_in[11];
    const float* b1     = (const float*)d_in[12];
    const float* a1     = (const float*)d_in[13];
    const float* g1     = (const float*)d_in[14];
    const float* be1    = (const float*)d_in[15];
    const float* w2     = (const float*)d_in[16];
    const float* b2     = (const float*)d_in[17];
    const float* a2     = (const float*)d_in[18];
    const float* g2     = (const float*)d_in[19];
    const float* be2    = (const float*)d_in[20];
    const float* w3     = (const float*)d_in[21];
    const float* b3     = (const float*)d_in[22];
    float* out = (float*)d_out;

    float* ws     = (float*)d_ws;
    float* part1t = ws;                            // [2*H1][NBLK] = 102400
    float* part2t = part1t + (size_t)2 * H1 * NBLK;// [2*H2][NBLK] = 40960
    float* sc1    = part2t + (size_t)2 * H2 * NBLK;// 256 (200 used)
    float* sh1    = sc1 + 256;
    float* sc2    = sh1 + 256;                     // 128 (80 used)
    float* sh2    = sc2 + 128;
    int*   ctrs   = (int*)(sh2 + 128);             // 2 counters (pad 64)
    float* feat   = (float*)(ctrs + 64);           // B*256
    float* y1     = feat + (size_t)B * 256;        // B*H1
    float* y2     = y1 + (size_t)B * H1;           // B*H2

    hipLaunchKernelGGL(k_attn,  dim3(B),    dim3(256), 0, stream,
                       user, item, rec, tu, t1, t2, t3,
                       w_att1, b_att1, w_att2, b_att2, feat, ctrs);
    hipLaunchKernelGGL(k_gemm1, dim3(NBLK), dim3(256), 0, stream,
                       feat, w1, b1, g1, be1, y1, part1t, sc1, sh1, ctrs);
    hipLaunchKernelGGL(k_mlp,   dim3(NBLK), dim3(256), 0, stream,
                       y1, sc1, sh1, a1, w2, b2, g2, be2, y2, part2t,
                       sc2, sh2, ctrs + 1);
    hipLaunchKernelGGL(k_final, dim3(NBLK), dim3(256), 0, stream,
                       y2, sc2, sh2, a2, w3, b3, out);
}

// Round 10
// 88.101 us; speedup vs baseline: 1.9586x; 1.9586x over previous
//
#include <hip/hip_runtime.h>
#include <math.h>

namespace {

constexpr int B   = 2048;
constexpr int L   = 200;
constexpr int E   = 96;    // 3 * D_FEAT
constexpr int U   = 64;
constexpr int NA  = 36;    // HID_ATT
constexpr int H1  = 200;
constexpr int H2  = 80;
constexpr int RB  = 8;     // rows per block for gemm1/mlp/final
constexpr int NBLK = B / RB;   // 256
constexpr int P1W = 512;   // padded part1 row width (s1 @ [0,256), s2 @ [256,512))
constexpr int P2W = 256;   // padded part2 row width (s1 @ [0,128), s2 @ [128,256))

__device__ __forceinline__ float sigf(float x) {
    return 1.0f / (1.0f + __expf(-x));
}

// VALU-only partial reduce within a 32-lane group: 4 DPP adds + shfl_xor(16).
template <int CTRL>
__device__ __forceinline__ float dppadd(float x) {
    int v = __builtin_amdgcn_update_dpp(0, __builtin_bit_cast(int, x),
                                        CTRL, 0xf, 0xf, true);
    return x + __builtin_bit_cast(float, v);
}
__device__ __forceinline__ float grp32_sum(float p) {
    p = dppadd<0xB1>(p);    // lane ^ 1
    p = dppadd<0x4E>(p);    // lane ^ 2
    p = dppadd<0x141>(p);   // row_half_mirror (^7)
    p = dppadd<0x140>(p);   // row_mirror (^15)
    p += __shfl_xor(p, 16);
    return p;
}

__device__ __forceinline__ void f4add(float4& a, const float4 b) {
    a.x += b.x; a.y += b.y; a.z += b.z; a.w += b.w;
}

// ---------------------------------------------------------------------------
// K1: one batch row per block. Per-block fold of the linear attention MLP,
// then 8 groups x 32 lanes x 25 items of fused score+browse. (validated r8)
// ---------------------------------------------------------------------------
__global__ __launch_bounds__(256) void k_attn(
    const int* __restrict__ user, const int* __restrict__ item,
    const int* __restrict__ rec,
    const float* __restrict__ tu, const float* __restrict__ t1,
    const float* __restrict__ t2, const float* __restrict__ t3,
    const float* __restrict__ w_att1, const float* __restrict__ b_att1,
    const float* __restrict__ w_att2, const float* __restrict__ b_att2,
    float* __restrict__ feat)
{
    __shared__ float s_v[292];
    __shared__ __align__(16) float s_feat[256];
    __shared__ float s_part[8][E];
    __shared__ __align__(16) int4 s_idx4[L];

    const int b = blockIdx.x, t = threadIdx.x;
    const int g = t >> 5, lane = t & 31;

    // ---- fold: s_v[0..95]=v1+v3 | [96..191]=v2-v3 | [192..287]=v4 | [288]=c
    for (int j = t; j < 289; j += 256) {
        float s;
        if (j < 96) {
            s = 0.f;
            #pragma unroll
            for (int k = 0; k < NA; ++k)
                s += w_att2[k] * (w_att1[k * 384 + j] + w_att1[k * 384 + 192 + j]);
        } else if (j < 192) {
            const int e = j - 96; s = 0.f;
            #pragma unroll
            for (int k = 0; k < NA; ++k)
                s += w_att2[k] * (w_att1[k * 384 + 96 + e] - w_att1[k * 384 + 192 + e]);
        } else if (j < 288) {
            const int e = j - 192; s = 0.f;
            #pragma unroll
            for (int k = 0; k < NA; ++k)
                s += w_att2[k] * w_att1[k * 384 + 288 + e];
        } else {
            s = b_att2[0];
            #pragma unroll
            for (int k = 0; k < NA; ++k) s += w_att2[k] * b_att1[k];
        }
        s_v[j] = s;
    }

    // ---- stage idx (padded to int4), q, user emb ---------------------------
    {
        int* si = (int*)s_idx4;
        for (int i = t; i < L * 3; i += 256) {
            const int v = rec[(size_t)b * L * 3 + i];
            si[(i / 3) * 4 + (i % 3)] = v;
        }
    }
    if (t < E) {                          // q = item_emb -> feat[0..95]
        const int f = t >> 5, e = t & 31;
        const float* tab = (f == 0) ? t1 : ((f == 1) ? t2 : t3);
        s_feat[t] = tab[item[b * 3 + f] * 32 + e];
    }
    if (t >= 192) s_feat[t] = tu[(size_t)user[b] * U + (t - 192)];
    __syncthreads();

    const float q0 = s_feat[lane], q1 = s_feat[32 + lane], q2 = s_feat[64 + lane];
    const float wa = s_v[96 + lane]  + q0 * s_v[192 + lane];
    const float wb = s_v[128 + lane] + q1 * s_v[224 + lane];
    const float wc = s_v[160 + lane] + q2 * s_v[256 + lane];
    float cb = q0 * s_v[lane] + q1 * s_v[32 + lane] + q2 * s_v[64 + lane];
    cb = grp32_sum(cb) + s_v[288];

    float a0 = 0.f, a1v = 0.f, a2v = 0.f;
    #pragma unroll 5
    for (int i = 0; i < 25; ++i) {
        const int4 iv = s_idx4[g * 25 + i];
        const float u0 = t1[iv.x * 32 + lane];
        const float u1 = t2[iv.y * 32 + lane];
        const float u2 = t3[iv.z * 32 + lane];
        float p = u0 * wa + u1 * wb + u2 * wc;
        p = grp32_sum(p);
        const float sc = (iv.x == 0) ? 0.f : (cb + p);
        a0 += sc * u0; a1v += sc * u1; a2v += sc * u2;
    }
    s_part[g][lane]      = a0;
    s_part[g][32 + lane] = a1v;
    s_part[g][64 + lane] = a2v;
    __syncthreads();

    if (t < E) {
        float s = 0.f;
        #pragma unroll
        for (int gg = 0; gg < 8; ++gg) s += s_part[gg][t];
        s_feat[96 + t] = s;
    }
    __syncthreads();

    feat[(size_t)b * 256 + t] = s_feat[t];
}

// ---------------------------------------------------------------------------
// K2: y1 = feat @ w1^T + b1 (8 rows/block); coalesced padded partial row
// part1[bid][0..199]=colsum, [256..455]=colsumsq, pad cols zeroed.
// ---------------------------------------------------------------------------
__global__ __launch_bounds__(256) void k_gemm1(
    const float* __restrict__ feat,
    const float* __restrict__ w1, const float* __restrict__ b1,
    float* __restrict__ y1, float* __restrict__ part1)
{
    __shared__ __align__(16) float s_f[RB * 256];
    const int t = threadIdx.x, b0 = blockIdx.x * RB;

    const float4* src = (const float4*)(feat + (size_t)b0 * 256);
    float4* dst = (float4*)s_f;
    dst[t] = src[t];
    dst[t + 256] = src[t + 256];
    __syncthreads();

    float s1 = 0.f, s2 = 0.f;
    if (t < H1) {
        const float4* wr = (const float4*)(w1 + t * 256);
        float acc[RB];
        const float bj = b1[t];
        #pragma unroll
        for (int bb = 0; bb < RB; ++bb) acc[bb] = bj;
        #pragma unroll 4
        for (int k = 0; k < 64; ++k) {
            const float4 w = wr[k];
            #pragma unroll
            for (int bb = 0; bb < RB; ++bb) {
                const float4 f = ((const float4*)(s_f + bb * 256))[k];
                acc[bb] += w.x * f.x + w.y * f.y + w.z * f.z + w.w * f.w;
            }
        }
        #pragma unroll
        for (int bb = 0; bb < RB; ++bb) {
            y1[(size_t)(b0 + bb) * H1 + t] = acc[bb];
            s1 += acc[bb]; s2 += acc[bb] * acc[bb];
        }
    }
    part1[(size_t)blockIdx.x * P1W + t]       = s1;   // zeros for t>=200
    part1[(size_t)blockIdx.x * P1W + 256 + t] = s2;
}

// ---------------------------------------------------------------------------
// K3: wave-coalesced redundant reduce of part1 -> dice-1 scale/shift in LDS;
// dice(y1); y2 = x @ w2^T + b2; padded part2 row per block.
// Reduce: wave w sweeps rows p=w,w+4,... reading the whole 2KB row as float4
// (128 independent loads/thread, MLP-pipelined) -- NOT r7's serial chain.
// ---------------------------------------------------------------------------
__global__ __launch_bounds__(256) void k_mlp(
    const float* __restrict__ y1, const float* __restrict__ part1,
    const float* __restrict__ a1, const float* __restrict__ g1,
    const float* __restrict__ be1,
    const float* __restrict__ w2, const float* __restrict__ b2,
    float* __restrict__ y2, float* __restrict__ part2)
{
    __shared__ __align__(16) float4 s_red4[4][128];     // 8 KB
    __shared__ float s_c1[H1], s_h1[H1], s_al[H1];
    __shared__ __align__(16) float s_x[RB][H1];
    __shared__ float s_p1[3][H2], s_p2[3][H2];
    const int t = threadIdx.x, b0 = blockIdx.x * RB;
    const int w = t >> 6, l = t & 63;

    // ---- stats reduce: rows of part1 [NBLK][512] ---------------------------
    {
        float4 a0 = {0.f, 0.f, 0.f, 0.f}, a1r = {0.f, 0.f, 0.f, 0.f};
        for (int p = w; p < NBLK; p += 4) {
            const float4* row = (const float4*)(part1 + (size_t)p * P1W);
            f4add(a0, row[l]);
            f4add(a1r, row[l + 64]);
        }
        s_red4[w][l]      = a0;
        s_red4[w][l + 64] = a1r;
    }
    __syncthreads();
    {
        const float* sr = (const float*)s_red4;   // [4][512] float view
        if (t < H1) {
            const float cs  = sr[t]       + sr[512 + t]       + sr[1024 + t]       + sr[1536 + t];
            const float cq  = sr[256 + t] + sr[512 + 256 + t] + sr[1024 + 256 + t] + sr[1536 + 256 + t];
            const float mean = cs * (1.f / B);
            float var = (cq - (float)B * mean * mean) * (1.f / (B - 1));
            var = fmaxf(var, 0.f);
            const float a = g1[t] * rsqrtf(var + 1e-8f);
            s_c1[t] = a; s_h1[t] = be1[t] - mean * a; s_al[t] = a1[t];
        }
    }
    __syncthreads();

    // ---- dice(y1) -----------------------------------------------------------
    for (int i = t; i < RB * H1; i += 256) {
        const int j = i % H1;
        const float xn = y1[(size_t)b0 * H1 + i] * s_c1[j] + s_h1[j];
        const float p  = sigf(xn);
        s_x[i / H1][j] = xn * (p + s_al[j] * (1.f - p));
    }
    __syncthreads();

    // ---- y2 = x @ w2^T + b2 (240 active threads) ----------------------------
    const int j = t % H2, rg = t / H2;    // rg 0..2 for t<240
    if (t < 240) {
        const int base = rg * 3;
        const int nb = (rg < 2) ? 3 : 2;  // rows 3/3/2 = 8
        const float4* wr = (const float4*)(w2 + j * H1);
        float acc[3];
        const float bj = b2[j];
        #pragma unroll
        for (int r = 0; r < 3; ++r) acc[r] = bj;
        #pragma unroll 2
        for (int k = 0; k < H1 / 4; ++k) {
            const float4 wv = wr[k];
            for (int r = 0; r < nb; ++r) {
                const float4 x = ((const float4*)s_x[base + r])[k];
                acc[r] += wv.x * x.x + wv.y * x.y + wv.z * x.z + wv.w * x.w;
            }
        }
        float s1 = 0.f, s2 = 0.f;
        for (int r = 0; r < nb; ++r) {
            y2[(size_t)(b0 + base + r) * H2 + j] = acc[r];
            s1 += acc[r]; s2 += acc[r] * acc[r];
        }
        s_p1[rg][j] = s1; s_p2[rg][j] = s2;
    }
    __syncthreads();

    // ---- padded part2 row: s1 @ [0,80), s2 @ [128,208), pad zeroed ----------
    if (t < 128) {
        const float v = (t < H2) ? (s_p1[0][t] + s_p1[1][t] + s_p1[2][t]) : 0.f;
        const float q = (t < H2) ? (s_p2[0][t] + s_p2[1][t] + s_p2[2][t]) : 0.f;
        part2[(size_t)blockIdx.x * P2W + t]       = v;
        part2[(size_t)blockIdx.x * P2W + 128 + t] = q;
    }
}

// ---------------------------------------------------------------------------
// K4: wave-coalesced redundant reduce of part2 -> dice-2 scale/shift; then
// dice(y2), dot w3, sigmoid. 8 rows/block, 32 lanes per row.
// ---------------------------------------------------------------------------
__global__ __launch_bounds__(256) void k_final(
    const float* __restrict__ y2, const float* __restrict__ part2,
    const float* __restrict__ a2, const float* __restrict__ g2,
    const float* __restrict__ be2,
    const float* __restrict__ w3, const float* __restrict__ b3,
    float* __restrict__ out)
{
    __shared__ __align__(16) float4 s_red4[4][64];      // 4 KB
    __shared__ float s_c[H2], s_s[H2], s_aw[H2], s_w3[H2];
    const int t = threadIdx.x, b0 = blockIdx.x * RB;
    const int w = t >> 6, l = t & 63;
    const int g = t >> 5, lane = t & 31;

    {
        float4 a0 = {0.f, 0.f, 0.f, 0.f};
        for (int p = w; p < NBLK; p += 4) {
            const float4* row = (const float4*)(part2 + (size_t)p * P2W);
            f4add(a0, row[l]);
        }
        s_red4[w][l] = a0;
    }
    __syncthreads();
    {
        const float* sr = (const float*)s_red4;   // [4][256] float view
        if (t < H2) {
            const float cs = sr[t]       + sr[256 + t]       + sr[512 + t]       + sr[768 + t];
            const float cq = sr[128 + t] + sr[256 + 128 + t] + sr[512 + 128 + t] + sr[768 + 128 + t];
            const float mean = cs * (1.f / B);
            float var = (cq - (float)B * mean * mean) * (1.f / (B - 1));
            var = fmaxf(var, 0.f);
            const float a = g2[t] * rsqrtf(var + 1e-8f);
            s_c[t] = a; s_s[t] = be2[t] - mean * a;
            s_aw[t] = a2[t]; s_w3[t] = w3[t];
        }
    }
    __syncthreads();

    const int r = b0 + g;
    float acc = 0.f;
    #pragma unroll
    for (int jj = 0; jj < 3; ++jj) {
        const int j = lane + jj * 32;
        if (j < H2) {
            const float xn = y2[(size_t)r * H2 + j] * s_c[j] + s_s[j];
            const float p  = sigf(xn);
            acc += xn * (p + s_aw[j] * (1.f - p)) * s_w3[j];
        }
    }
    acc = grp32_sum(acc);
    if (lane == 0) out[r] = sigf(acc + b3[0]);
}

} // namespace

extern "C" void kernel_launch(void* const* d_in, const int* in_sizes, int n_in,
                              void* d_out, int out_size, void* d_ws, size_t ws_size,
                              hipStream_t stream) {
    const int*   user   = (const int*)d_in[0];
    const int*   item   = (const int*)d_in[1];
    const int*   rec    = (const int*)d_in[2];
    const float* tu     = (const float*)d_in[3];
    const float* t1     = (const float*)d_in[4];
    const float* t2     = (const float*)d_in[5];
    const float* t3     = (const float*)d_in[6];
    const float* w_att1 = (const float*)d_in[7];
    const float* b_att1 = (const float*)d_in[8];
    const float* w_att2 = (const float*)d_in[9];
    const float* b_att2 = (const float*)d_in[10];
    const float* w1     = (const float*)d_in[11];
    const float* b1     = (const float*)d_in[12];
    const float* a1     = (const float*)d_in[13];
    const float* g1     = (const float*)d_in[14];
    const float* be1    = (const float*)d_in[15];
    const float* w2     = (const float*)d_in[16];
    const float* b2     = (const float*)d_in[17];
    const float* a2     = (const float*)d_in[18];
    const float* g2     = (const float*)d_in[19];
    const float* be2    = (const float*)d_in[20];
    const float* w3     = (const float*)d_in[21];
    const float* b3     = (const float*)d_in[22];
    float* out = (float*)d_out;

    float* ws    = (float*)d_ws;
    float* part1 = ws;                            // [256][512] = 131072
    float* part2 = part1 + (size_t)NBLK * P1W;    // [256][256] = 65536
    float* feat  = part2 + (size_t)NBLK * P2W;    // B*256
    float* y1    = feat + (size_t)B * 256;        // B*H1
    float* y2    = y1 + (size_t)B * H1;           // B*H2

    hipLaunchKernelGGL(k_attn,  dim3(B),    dim3(256), 0, stream,
                       user, item, rec, tu, t1, t2, t3,
                       w_att1, b_att1, w_att2, b_att2, feat);
    hipLaunchKernelGGL(k_gemm1, dim3(NBLK), dim3(256), 0, stream,
                       feat, w1, b1, y1, part1);
    hipLaunchKernelGGL(k_mlp,   dim3(NBLK), dim3(256), 0, stream,
                       y1, part1, a1, g1, be1, w2, b2, y2, part2);
    hipLaunchKernelGGL(k_final, dim3(NBLK), dim3(256), 0, stream,
                       y2, part2, a2, g2, be2, w3, b3, out);
}

// Round 11
// 58.573 us; speedup vs baseline: 2.9460x; 1.5041x over previous
//
#include <hip/hip_runtime.h>
#include <math.h>

namespace {

constexpr int B   = 2048;
constexpr int L   = 200;
constexpr int E   = 96;    // 3 * D_FEAT
constexpr int U   = 64;
constexpr int NA  = 36;    // HID_ATT
constexpr int H1  = 200;
constexpr int H2  = 80;
constexpr int RB  = 8;     // rows per block for gemm1/mlp/final
constexpr int NBLK = B / RB;   // 256

__device__ __forceinline__ float sigf(float x) {
    return 1.0f / (1.0f + __expf(-x));
}

// DPP partial sums. After the 4 ops below, every lane of each 16-lane row
// holds the row's full sum (quad ^1, ^2, then cross-quad and cross-half
// mirrors). VALU only -- no DS pipe.
template <int CTRL>
__device__ __forceinline__ float dppadd(float x) {
    int v = __builtin_amdgcn_update_dpp(0, __builtin_bit_cast(int, x),
                                        CTRL, 0xf, 0xf, true);
    return x + __builtin_bit_cast(float, v);
}
__device__ __forceinline__ float grp16_sum(float p) {
    p = dppadd<0xB1>(p);    // quad_perm [1,0,3,2] : ^1
    p = dppadd<0x4E>(p);    // quad_perm [2,3,0,1] : ^2
    p = dppadd<0x141>(p);   // row_half_mirror     : other quad
    p = dppadd<0x140>(p);   // row_mirror          : other 8-half
    return p;
}
__device__ __forceinline__ float grp32_sum(float p) {
    p = grp16_sum(p);
    p += __shfl_xor(p, 16);
    return p;
}

// ---------------------------------------------------------------------------
// K1: one batch row per block. Per-block fold of the linear attention MLP,
// then 16 groups x 16 lanes; each group serially processes items l = g+16*i.
// Score reduce = 4 DPP ops (no DS). Lane ln owns features ln+16*m, m=0..5.
// ---------------------------------------------------------------------------
__global__ __launch_bounds__(256) void k_attn(
    const int* __restrict__ user, const int* __restrict__ item,
    const int* __restrict__ rec,
    const float* __restrict__ tu, const float* __restrict__ t1,
    const float* __restrict__ t2, const float* __restrict__ t3,
    const float* __restrict__ w_att1, const float* __restrict__ b_att1,
    const float* __restrict__ w_att2, const float* __restrict__ b_att2,
    float* __restrict__ feat)
{
    __shared__ float s_v[292];
    __shared__ __align__(16) float s_feat[256];
    __shared__ float s_part[16][E];
    __shared__ __align__(16) int4 s_idx4[L];

    const int b = blockIdx.x, t = threadIdx.x;
    const int g = t >> 4, ln = t & 15;

    // ---- fold: s_v[0..95]=v1+v3 | [96..191]=v2-v3 | [192..287]=v4 | [288]=c
    for (int j = t; j < 289; j += 256) {
        float s;
        if (j < 96) {
            s = 0.f;
            #pragma unroll
            for (int k = 0; k < NA; ++k)
                s += w_att2[k] * (w_att1[k * 384 + j] + w_att1[k * 384 + 192 + j]);
        } else if (j < 192) {
            const int e = j - 96; s = 0.f;
            #pragma unroll
            for (int k = 0; k < NA; ++k)
                s += w_att2[k] * (w_att1[k * 384 + 96 + e] - w_att1[k * 384 + 192 + e]);
        } else if (j < 288) {
            const int e = j - 192; s = 0.f;
            #pragma unroll
            for (int k = 0; k < NA; ++k)
                s += w_att2[k] * w_att1[k * 384 + 288 + e];
        } else {
            s = b_att2[0];
            #pragma unroll
            for (int k = 0; k < NA; ++k) s += w_att2[k] * b_att1[k];
        }
        s_v[j] = s;
    }

    // ---- stage idx (padded to int4), q, user emb ---------------------------
    {
        int* si = (int*)s_idx4;
        for (int i = t; i < L * 3; i += 256) {
            const int v = rec[(size_t)b * L * 3 + i];
            si[(i / 3) * 4 + (i % 3)] = v;
        }
    }
    if (t < E) {                          // q = item_emb -> feat[0..95]
        const int f = t >> 5, e = t & 31;
        const float* tab = (f == 0) ? t1 : ((f == 1) ? t2 : t3);
        s_feat[t] = tab[item[b * 3 + f] * 32 + e];
    }
    if (t >= 192) s_feat[t] = tu[(size_t)user[b] * U + (t - 192)];
    __syncthreads();

    // ---- per-lane score weights for features e = ln + 16*m -----------------
    float w[6], cb = 0.f;
    #pragma unroll
    for (int m = 0; m < 6; ++m) {
        const int e = ln + 16 * m;
        const float q = s_feat[e];
        w[m] = s_v[96 + e] + q * s_v[192 + e];
        cb  += q * s_v[e];
    }
    cb = grp16_sum(cb) + s_v[288];

    // ---- fused score + browse: items l = g + 16*i --------------------------
    float acc[6];
    #pragma unroll
    for (int m = 0; m < 6; ++m) acc[m] = 0.f;
    #pragma unroll 4
    for (int i = 0; i < 13; ++i) {
        const int l = g + (i << 4);
        if (l < L) {
            const int4 iv = s_idx4[l];
            const float u0 = t1[iv.x * 32 + ln];
            const float u1 = t1[iv.x * 32 + 16 + ln];
            const float u2 = t2[iv.y * 32 + ln];
            const float u3 = t2[iv.y * 32 + 16 + ln];
            const float u4 = t3[iv.z * 32 + ln];
            const float u5 = t3[iv.z * 32 + 16 + ln];
            float p = u0 * w[0] + u1 * w[1] + u2 * w[2]
                    + u3 * w[3] + u4 * w[4] + u5 * w[5];
            p = grp16_sum(p);
            const float sc = (iv.x == 0) ? 0.f : (cb + p);
            acc[0] += sc * u0; acc[1] += sc * u1; acc[2] += sc * u2;
            acc[3] += sc * u3; acc[4] += sc * u4; acc[5] += sc * u5;
        }
    }
    #pragma unroll
    for (int m = 0; m < 6; ++m) s_part[g][16 * m + ln] = acc[m];
    __syncthreads();

    if (t < E) {                          // browse -> feat[96..191]
        float s = 0.f;
        #pragma unroll
        for (int gg = 0; gg < 16; ++gg) s += s_part[gg][t];
        s_feat[96 + t] = s;
    }
    __syncthreads();

    feat[(size_t)b * 256 + t] = s_feat[t];
}

// ---------------------------------------------------------------------------
// K2: y1 = feat @ w1^T + b1 (8 rows/block); per-block column partials to
// part1[blk][0..199]=sum, [200..399]=sumsq. No atomics. (validated r8)
// ---------------------------------------------------------------------------
__global__ __launch_bounds__(256) void k_gemm1(
    const float* __restrict__ feat,
    const float* __restrict__ w1, const float* __restrict__ b1,
    float* __restrict__ y1, float* __restrict__ part1)
{
    __shared__ __align__(16) float s_f[RB * 256];
    const int t = threadIdx.x, b0 = blockIdx.x * RB;

    const float4* src = (const float4*)(feat + (size_t)b0 * 256);
    float4* dst = (float4*)s_f;
    dst[t] = src[t];
    dst[t + 256] = src[t + 256];
    __syncthreads();

    if (t < H1) {
        const float4* wr = (const float4*)(w1 + t * 256);
        float acc[RB];
        const float bj = b1[t];
        #pragma unroll
        for (int bb = 0; bb < RB; ++bb) acc[bb] = bj;
        #pragma unroll 4
        for (int k = 0; k < 64; ++k) {
            const float4 w = wr[k];
            #pragma unroll
            for (int bb = 0; bb < RB; ++bb) {
                const float4 f = ((const float4*)(s_f + bb * 256))[k];
                acc[bb] += w.x * f.x + w.y * f.y + w.z * f.z + w.w * f.w;
            }
        }
        float s1 = 0.f, s2 = 0.f;
        #pragma unroll
        for (int bb = 0; bb < RB; ++bb) {
            y1[(size_t)(b0 + bb) * H1 + t] = acc[bb];
            s1 += acc[bb]; s2 += acc[bb] * acc[bb];
        }
        part1[(size_t)blockIdx.x * 400 + t]       = s1;
        part1[(size_t)blockIdx.x * 400 + 200 + t] = s2;
    }
}

// ---------------------------------------------------------------------------
// K2b/K3b: finalize column stats from partials. One block per column;
// thread t reads partial row t (2 loads), LDS tree reduce, write sc/sh.
// ---------------------------------------------------------------------------
template <int NCOL, int STRIDE>
__global__ __launch_bounds__(256) void k_stats(
    const float* __restrict__ part, const float* __restrict__ g,
    const float* __restrict__ be,
    float* __restrict__ sc, float* __restrict__ sh)
{
    __shared__ float rs[256], rq[256];
    const int j = blockIdx.x, t = threadIdx.x;
    rs[t] = part[(size_t)t * STRIDE + j];
    rq[t] = part[(size_t)t * STRIDE + NCOL + j];
    __syncthreads();
    #pragma unroll
    for (int o = 128; o > 0; o >>= 1) {
        if (t < o) { rs[t] += rs[t + o]; rq[t] += rq[t + o]; }
        __syncthreads();
    }
    if (t == 0) {
        const float mean = rs[0] * (1.f / B);
        float var = (rq[0] - (float)B * mean * mean) * (1.f / (B - 1));
        var = fmaxf(var, 0.f);
        const float a = g[j] * rsqrtf(var + 1e-8f);
        sc[j] = a;
        sh[j] = be[j] - mean * a;
    }
}

// ---------------------------------------------------------------------------
// K3: dice(y1) -> y2 = x @ w2^T + b2 (8 rows/block); part2 stores.
// ---------------------------------------------------------------------------
__global__ __launch_bounds__(256) void k_mlp(
    const float* __restrict__ y1,
    const float* __restrict__ sc1, const float* __restrict__ sh1,
    const float* __restrict__ a1,
    const float* __restrict__ w2, const float* __restrict__ b2,
    float* __restrict__ y2, float* __restrict__ part2)
{
    __shared__ float s_c1[H1], s_h1[H1], s_al[H1];
    __shared__ __align__(16) float s_x[RB][H1];
    __shared__ float s_p1[3][H2], s_p2[3][H2];
    const int t = threadIdx.x, b0 = blockIdx.x * RB;

    if (t < H1) { s_c1[t] = sc1[t]; s_h1[t] = sh1[t]; s_al[t] = a1[t]; }
    __syncthreads();

    for (int i = t; i < RB * H1; i += 256) {
        const int j = i % H1;
        const float xn = y1[(size_t)b0 * H1 + i] * s_c1[j] + s_h1[j];
        const float p  = sigf(xn);
        s_x[i / H1][j] = xn * (p + s_al[j] * (1.f - p));
    }
    __syncthreads();

    const int j = t % H2, rg = t / H2;    // rg 0..2 for t<240
    if (t < 240) {
        const int base = rg * 3;
        const int nb = (rg < 2) ? 3 : 2;  // rows 3/3/2 = 8
        const float4* wr = (const float4*)(w2 + j * H1);
        float acc[3];
        const float bj = b2[j];
        #pragma unroll
        for (int r = 0; r < 3; ++r) acc[r] = bj;
        #pragma unroll 2
        for (int k = 0; k < H1 / 4; ++k) {
            const float4 w = wr[k];
            for (int r = 0; r < nb; ++r) {
                const float4 x = ((const float4*)s_x[base + r])[k];
                acc[r] += w.x * x.x + w.y * x.y + w.z * x.z + w.w * x.w;
            }
        }
        float s1 = 0.f, s2 = 0.f;
        for (int r = 0; r < nb; ++r) {
            y2[(size_t)(b0 + base + r) * H2 + j] = acc[r];
            s1 += acc[r]; s2 += acc[r] * acc[r];
        }
        s_p1[rg][j] = s1; s_p2[rg][j] = s2;
    }
    __syncthreads();
    if (t < H2) {
        part2[(size_t)blockIdx.x * 160 + t]      = s_p1[0][t] + s_p1[1][t] + s_p1[2][t];
        part2[(size_t)blockIdx.x * 160 + 80 + t] = s_p2[0][t] + s_p2[1][t] + s_p2[2][t];
    }
}

// ---------------------------------------------------------------------------
// K4: dice(y2), dot w3, sigmoid. 8 rows/block, 32 lanes per row.
// ---------------------------------------------------------------------------
__global__ __launch_bounds__(256) void k_final(
    const float* __restrict__ y2,
    const float* __restrict__ sc2, const float* __restrict__ sh2,
    const float* __restrict__ a2,
    const float* __restrict__ w3, const float* __restrict__ b3,
    float* __restrict__ out)
{
    __shared__ float s_c[H2], s_s[H2], s_aw[H2], s_w3[H2];
    const int t = threadIdx.x, b0 = blockIdx.x * RB;
    const int g = t >> 5, lane = t & 31;

    if (t < H2) {
        s_c[t] = sc2[t]; s_s[t] = sh2[t];
        s_aw[t] = a2[t]; s_w3[t] = w3[t];
    }
    __syncthreads();

    const int r = b0 + g;
    float acc = 0.f;
    #pragma unroll
    for (int jj = 0; jj < 3; ++jj) {
        const int j = lane + jj * 32;
        if (j < H2) {
            const float xn = y2[(size_t)r * H2 + j] * s_c[j] + s_s[j];
            const float p  = sigf(xn);
            acc += xn * (p + s_aw[j] * (1.f - p)) * s_w3[j];
        }
    }
    acc = grp32_sum(acc);
    if (lane == 0) out[r] = sigf(acc + b3[0]);
}

} // namespace

extern "C" void kernel_launch(void* const* d_in, const int* in_sizes, int n_in,
                              void* d_out, int out_size, void* d_ws, size_t ws_size,
                              hipStream_t stream) {
    const int*   user   = (const int*)d_in[0];
    const int*   item   = (const int*)d_in[1];
    const int*   rec    = (const int*)d_in[2];
    const float* tu     = (const float*)d_in[3];
    const float* t1     = (const float*)d_in[4];
    const float* t2     = (const float*)d_in[5];
    const float* t3     = (const float*)d_in[6];
    const float* w_att1 = (const float*)d_in[7];
    const float* b_att1 = (const float*)d_in[8];
    const float* w_att2 = (const float*)d_in[9];
    const float* b_att2 = (const float*)d_in[10];
    const float* w1     = (const float*)d_in[11];
    const float* b1     = (const float*)d_in[12];
    const float* a1     = (const float*)d_in[13];
    const float* g1     = (const float*)d_in[14];
    const float* be1    = (const float*)d_in[15];
    const float* w2     = (const float*)d_in[16];
    const float* b2     = (const float*)d_in[17];
    const float* a2     = (const float*)d_in[18];
    const float* g2     = (const float*)d_in[19];
    const float* be2    = (const float*)d_in[20];
    const float* w3     = (const float*)d_in[21];
    const float* b3     = (const float*)d_in[22];
    float* out = (float*)d_out;

    float* ws    = (float*)d_ws;
    float* part1 = ws;                           // 256*400
    float* part2 = part1 + (size_t)NBLK * 400;   // 256*160
    float* sc1   = part2 + (size_t)NBLK * 160;   // 256 (200 used)
    float* sh1   = sc1 + 256;                    // 256
    float* sc2   = sh1 + 256;                    // 128 (80 used)
    float* sh2   = sc2 + 128;                    // 128
    float* feat  = sh2 + 128;                    // B*256
    float* y1    = feat + (size_t)B * 256;       // B*H1
    float* y2    = y1 + (size_t)B * H1;          // B*H2

    hipLaunchKernelGGL(k_attn,  dim3(B),    dim3(256), 0, stream,
                       user, item, rec, tu, t1, t2, t3,
                       w_att1, b_att1, w_att2, b_att2, feat);
    hipLaunchKernelGGL(k_gemm1, dim3(NBLK), dim3(256), 0, stream,
                       feat, w1, b1, y1, part1);
    hipLaunchKernelGGL((k_stats<H1, 400>), dim3(H1), dim3(256), 0, stream,
                       part1, g1, be1, sc1, sh1);
    hipLaunchKernelGGL(k_mlp,   dim3(NBLK), dim3(256), 0, stream,
                       y1, sc1, sh1, a1, w2, b2, y2, part2);
    hipLaunchKernelGGL((k_stats<H2, 160>), dim3(H2), dim3(256), 0, stream,
                       part2, g2, be2, sc2, sh2);
    hipLaunchKernelGGL(k_final, dim3(NBLK), dim3(256), 0, stream,
                       y2, sc2, sh2, a2, w3, b3, out);
}

// Round 12
// 52.453 us; speedup vs baseline: 3.2897x; 1.1167x over previous
//
#include <hip/hip_runtime.h>
#include <math.h>

namespace {

constexpr int B   = 2048;
constexpr int L   = 200;
constexpr int E   = 96;    // 3 * D_FEAT
constexpr int U   = 64;
constexpr int NA  = 36;    // HID_ATT
constexpr int H1  = 200;
constexpr int H2  = 80;
constexpr int RB  = 8;     // rows per block, gemm1 / final
constexpr int RBM = 4;     // rows per block, mlp
constexpr int NBLK  = B / RB;    // 256
constexpr int NBLKM = B / RBM;   // 512

__device__ __forceinline__ float sigf(float x) {
    return 1.0f / (1.0f + __expf(-x));
}

// DPP partial sums: after 4 ops every lane of a 16-lane row holds the row sum.
template <int CTRL>
__device__ __forceinline__ float dppadd(float x) {
    int v = __builtin_amdgcn_update_dpp(0, __builtin_bit_cast(int, x),
                                        CTRL, 0xf, 0xf, true);
    return x + __builtin_bit_cast(float, v);
}
__device__ __forceinline__ float grp16_sum(float p) {
    p = dppadd<0xB1>(p);    // quad_perm ^1
    p = dppadd<0x4E>(p);    // quad_perm ^2
    p = dppadd<0x141>(p);   // row_half_mirror
    p = dppadd<0x140>(p);   // row_mirror
    return p;
}
__device__ __forceinline__ float grp32_sum(float p) {
    p = grp16_sum(p);
    p += __shfl_xor(p, 16);
    return p;
}

// ---------------------------------------------------------------------------
// K1: one batch row per block. Per-block fold of the linear attention MLP,
// then 16 groups x 16 lanes; lane ln owns feature pairs e = 32f + 2ln + {0,1}
// -> each item costs 3 float2 gathers (half the VMEM issues of r11).
// ---------------------------------------------------------------------------
__global__ __launch_bounds__(256) void k_attn(
    const int* __restrict__ user, const int* __restrict__ item,
    const int* __restrict__ rec,
    const float* __restrict__ tu, const float* __restrict__ t1,
    const float* __restrict__ t2, const float* __restrict__ t3,
    const float* __restrict__ w_att1, const float* __restrict__ b_att1,
    const float* __restrict__ w_att2, const float* __restrict__ b_att2,
    float* __restrict__ feat)
{
    __shared__ float s_v[292];
    __shared__ __align__(16) float s_feat[256];
    __shared__ float s_part[16][E];
    __shared__ __align__(16) int4 s_idx4[L];

    const int b = blockIdx.x, t = threadIdx.x;
    const int g = t >> 4, ln = t & 15;

    // ---- fold: s_v[0..95]=v1+v3 | [96..191]=v2-v3 | [192..287]=v4 | [288]=c
    for (int j = t; j < 289; j += 256) {
        float s;
        if (j < 96) {
            s = 0.f;
            #pragma unroll
            for (int k = 0; k < NA; ++k)
                s += w_att2[k] * (w_att1[k * 384 + j] + w_att1[k * 384 + 192 + j]);
        } else if (j < 192) {
            const int e = j - 96; s = 0.f;
            #pragma unroll
            for (int k = 0; k < NA; ++k)
                s += w_att2[k] * (w_att1[k * 384 + 96 + e] - w_att1[k * 384 + 192 + e]);
        } else if (j < 288) {
            const int e = j - 192; s = 0.f;
            #pragma unroll
            for (int k = 0; k < NA; ++k)
                s += w_att2[k] * w_att1[k * 384 + 288 + e];
        } else {
            s = b_att2[0];
            #pragma unroll
            for (int k = 0; k < NA; ++k) s += w_att2[k] * b_att1[k];
        }
        s_v[j] = s;
    }

    // ---- stage idx (padded to int4), q, user emb ---------------------------
    {
        int* si = (int*)s_idx4;
        for (int i = t; i < L * 3; i += 256) {
            const int v = rec[(size_t)b * L * 3 + i];
            si[(i / 3) * 4 + (i % 3)] = v;
        }
    }
    if (t < E) {                          // q = item_emb -> feat[0..95]
        const int f = t >> 5, e = t & 31;
        const float* tab = (f == 0) ? t1 : ((f == 1) ? t2 : t3);
        s_feat[t] = tab[item[b * 3 + f] * 32 + e];
    }
    if (t >= 192) s_feat[t] = tu[(size_t)user[b] * U + (t - 192)];
    __syncthreads();

    // ---- per-lane score weights for feature pairs e = 32f + 2ln + c --------
    float w[6], cb = 0.f;
    #pragma unroll
    for (int f = 0; f < 3; ++f) {
        #pragma unroll
        for (int c = 0; c < 2; ++c) {
            const int e = 32 * f + 2 * ln + c;
            const float q = s_feat[e];
            w[2 * f + c] = s_v[96 + e] + q * s_v[192 + e];
            cb += q * s_v[e];
        }
    }
    cb = grp16_sum(cb) + s_v[288];

    // ---- fused score + browse: items l = g + 16*i, 3 float2 gathers each ---
    float acc[6];
    #pragma unroll
    for (int m = 0; m < 6; ++m) acc[m] = 0.f;
    #pragma unroll 4
    for (int i = 0; i < 13; ++i) {
        const int l = g + (i << 4);
        if (l < L) {
            const int4 iv = s_idx4[l];
            const float2 u0 = *(const float2*)(t1 + iv.x * 32 + 2 * ln);
            const float2 u1 = *(const float2*)(t2 + iv.y * 32 + 2 * ln);
            const float2 u2 = *(const float2*)(t3 + iv.z * 32 + 2 * ln);
            float p = u0.x * w[0] + u0.y * w[1] + u1.x * w[2]
                    + u1.y * w[3] + u2.x * w[4] + u2.y * w[5];
            p = grp16_sum(p);
            const float sc = (iv.x == 0) ? 0.f : (cb + p);
            acc[0] += sc * u0.x; acc[1] += sc * u0.y;
            acc[2] += sc * u1.x; acc[3] += sc * u1.y;
            acc[4] += sc * u2.x; acc[5] += sc * u2.y;
        }
    }
    #pragma unroll
    for (int f = 0; f < 3; ++f) {
        #pragma unroll
        for (int c = 0; c < 2; ++c)
            s_part[g][32 * f + 2 * ln + c] = acc[2 * f + c];
    }
    __syncthreads();

    if (t < E) {                          // browse -> feat[96..191]
        float s = 0.f;
        #pragma unroll
        for (int gg = 0; gg < 16; ++gg) s += s_part[gg][t];
        s_feat[96 + t] = s;
    }
    __syncthreads();

    feat[(size_t)b * 256 + t] = s_feat[t];
}

// ---------------------------------------------------------------------------
// K2: y1 = feat @ w1^T + b1 (8 rows/block); per-block column partials to
// part1[blk][0..199]=sum, [200..399]=sumsq. (validated r8/r11)
// ---------------------------------------------------------------------------
__global__ __launch_bounds__(256) void k_gemm1(
    const float* __restrict__ feat,
    const float* __restrict__ w1, const float* __restrict__ b1,
    float* __restrict__ y1, float* __restrict__ part1)
{
    __shared__ __align__(16) float s_f[RB * 256];
    const int t = threadIdx.x, b0 = blockIdx.x * RB;

    const float4* src = (const float4*)(feat + (size_t)b0 * 256);
    float4* dst = (float4*)s_f;
    dst[t] = src[t];
    dst[t + 256] = src[t + 256];
    __syncthreads();

    if (t < H1) {
        const float4* wr = (const float4*)(w1 + t * 256);
        float acc[RB];
        const float bj = b1[t];
        #pragma unroll
        for (int bb = 0; bb < RB; ++bb) acc[bb] = bj;
        #pragma unroll 4
        for (int k = 0; k < 64; ++k) {
            const float4 w = wr[k];
            #pragma unroll
            for (int bb = 0; bb < RB; ++bb) {
                const float4 f = ((const float4*)(s_f + bb * 256))[k];
                acc[bb] += w.x * f.x + w.y * f.y + w.z * f.z + w.w * f.w;
            }
        }
        float s1 = 0.f, s2 = 0.f;
        #pragma unroll
        for (int bb = 0; bb < RB; ++bb) {
            y1[(size_t)(b0 + bb) * H1 + t] = acc[bb];
            s1 += acc[bb]; s2 += acc[bb] * acc[bb];
        }
        part1[(size_t)blockIdx.x * 400 + t]       = s1;
        part1[(size_t)blockIdx.x * 400 + 200 + t] = s2;
    }
}

// ---------------------------------------------------------------------------
// Stats finalize: one block per column; threads sweep NROWS partial rows
// (grid-stride), LDS tree reduce, write sc/sh.
// ---------------------------------------------------------------------------
template <int NCOL, int STRIDE, int NROWS>
__global__ __launch_bounds__(256) void k_stats(
    const float* __restrict__ part, const float* __restrict__ g,
    const float* __restrict__ be,
    float* __restrict__ sc, float* __restrict__ sh)
{
    __shared__ float rs[256], rq[256];
    const int j = blockIdx.x, t = threadIdx.x;
    float s = 0.f, q = 0.f;
    #pragma unroll
    for (int r = t; r < NROWS; r += 256) {
        s += part[(size_t)r * STRIDE + j];
        q += part[(size_t)r * STRIDE + NCOL + j];
    }
    rs[t] = s; rq[t] = q;
    __syncthreads();
    #pragma unroll
    for (int o = 128; o > 0; o >>= 1) {
        if (t < o) { rs[t] += rs[t + o]; rq[t] += rq[t + o]; }
        __syncthreads();
    }
    if (t == 0) {
        const float mean = rs[0] * (1.f / B);
        float var = (rq[0] - (float)B * mean * mean) * (1.f / (B - 1));
        var = fmaxf(var, 0.f);
        const float a = g[j] * rsqrtf(var + 1e-8f);
        sc[j] = a;
        sh[j] = be[j] - mean * a;
    }
}

// ---------------------------------------------------------------------------
// K3: dice(y1) -> y2 = x @ w2^T + b2. RBM=4 rows/block (grid 512 = 2/CU for
// latency overlap). 160 active threads in GEMM2: thread (rr=t/80, j=t%80)
// computes rows rr and rr+2.
// ---------------------------------------------------------------------------
__global__ __launch_bounds__(256) void k_mlp(
    const float* __restrict__ y1,
    const float* __restrict__ sc1, const float* __restrict__ sh1,
    const float* __restrict__ a1,
    const float* __restrict__ w2, const float* __restrict__ b2,
    float* __restrict__ y2, float* __restrict__ part2)
{
    __shared__ float s_c1[H1], s_h1[H1], s_al[H1];
    __shared__ __align__(16) float s_x[RBM][H1];
    __shared__ float s_p1[2][H2], s_p2[2][H2];
    const int t = threadIdx.x, b0 = blockIdx.x * RBM;

    if (t < H1) { s_c1[t] = sc1[t]; s_h1[t] = sh1[t]; s_al[t] = a1[t]; }
    __syncthreads();

    for (int i = t; i < RBM * H1; i += 256) {
        const int j = i % H1;
        const float xn = y1[(size_t)b0 * H1 + i] * s_c1[j] + s_h1[j];
        const float p  = sigf(xn);
        s_x[i / H1][j] = xn * (p + s_al[j] * (1.f - p));
    }
    __syncthreads();

    const int j = t % H2, rr = t / H2;    // rr 0..1 for t<160
    if (t < 160) {
        const float4* wr = (const float4*)(w2 + j * H1);
        const float bj = b2[j];
        float acc0 = bj, acc1 = bj;       // rows rr, rr+2
        #pragma unroll 2
        for (int k = 0; k < H1 / 4; ++k) {
            const float4 w = wr[k];
            const float4 x0 = ((const float4*)s_x[rr])[k];
            const float4 x1 = ((const float4*)s_x[rr + 2])[k];
            acc0 += w.x * x0.x + w.y * x0.y + w.z * x0.z + w.w * x0.w;
            acc1 += w.x * x1.x + w.y * x1.y + w.z * x1.z + w.w * x1.w;
        }
        y2[(size_t)(b0 + rr) * H2 + j]     = acc0;
        y2[(size_t)(b0 + rr + 2) * H2 + j] = acc1;
        s_p1[rr][j] = acc0 + acc1;
        s_p2[rr][j] = acc0 * acc0 + acc1 * acc1;
    }
    __syncthreads();
    if (t < H2) {
        part2[(size_t)blockIdx.x * 160 + t]      = s_p1[0][t] + s_p1[1][t];
        part2[(size_t)blockIdx.x * 160 + 80 + t] = s_p2[0][t] + s_p2[1][t];
    }
}

// ---------------------------------------------------------------------------
// K4: dice(y2), dot w3, sigmoid. 8 rows/block, 32 lanes per row.
// ---------------------------------------------------------------------------
__global__ __launch_bounds__(256) void k_final(
    const float* __restrict__ y2,
    const float* __restrict__ sc2, const float* __restrict__ sh2,
    const float* __restrict__ a2,
    const float* __restrict__ w3, const float* __restrict__ b3,
    float* __restrict__ out)
{
    __shared__ float s_c[H2], s_s[H2], s_aw[H2], s_w3[H2];
    const int t = threadIdx.x, b0 = blockIdx.x * RB;
    const int g = t >> 5, lane = t & 31;

    if (t < H2) {
        s_c[t] = sc2[t]; s_s[t] = sh2[t];
        s_aw[t] = a2[t]; s_w3[t] = w3[t];
    }
    __syncthreads();

    const int r = b0 + g;
    float acc = 0.f;
    #pragma unroll
    for (int jj = 0; jj < 3; ++jj) {
        const int j = lane + jj * 32;
        if (j < H2) {
            const float xn = y2[(size_t)r * H2 + j] * s_c[j] + s_s[j];
            const float p  = sigf(xn);
            acc += xn * (p + s_aw[j] * (1.f - p)) * s_w3[j];
        }
    }
    acc = grp32_sum(acc);
    if (lane == 0) out[r] = sigf(acc + b3[0]);
}

} // namespace

extern "C" void kernel_launch(void* const* d_in, const int* in_sizes, int n_in,
                              void* d_out, int out_size, void* d_ws, size_t ws_size,
                              hipStream_t stream) {
    const int*   user   = (const int*)d_in[0];
    const int*   item   = (const int*)d_in[1];
    const int*   rec    = (const int*)d_in[2];
    const float* tu     = (const float*)d_in[3];
    const float* t1     = (const float*)d_in[4];
    const float* t2     = (const float*)d_in[5];
    const float* t3     = (const float*)d_in[6];
    const float* w_att1 = (const float*)d_in[7];
    const float* b_att1 = (const float*)d_in[8];
    const float* w_att2 = (const float*)d_in[9];
    const float* b_att2 = (const float*)d_in[10];
    const float* w1     = (const float*)d_in[11];
    const float* b1     = (const float*)d_in[12];
    const float* a1     = (const float*)d_in[13];
    const float* g1     = (const float*)d_in[14];
    const float* be1    = (const float*)d_in[15];
    const float* w2     = (const float*)d_in[16];
    const float* b2     = (const float*)d_in[17];
    const float* a2     = (const float*)d_in[18];
    const float* g2     = (const float*)d_in[19];
    const float* be2    = (const float*)d_in[20];
    const float* w3     = (const float*)d_in[21];
    const float* b3     = (const float*)d_in[22];
    float* out = (float*)d_out;

    float* ws    = (float*)d_ws;
    float* part1 = ws;                            // 256*400
    float* part2 = part1 + (size_t)NBLK * 400;    // 512*160
    float* sc1   = part2 + (size_t)NBLKM * 160;   // 256 (200 used)
    float* sh1   = sc1 + 256;                     // 256
    float* sc2   = sh1 + 256;                     // 128 (80 used)
    float* sh2   = sc2 + 128;                     // 128
    float* feat  = sh2 + 128;                     // B*256
    float* y1    = feat + (size_t)B * 256;        // B*H1
    float* y2    = y1 + (size_t)B * H1;           // B*H2

    hipLaunchKernelGGL(k_attn,  dim3(B),     dim3(256), 0, stream,
                       user, item, rec, tu, t1, t2, t3,
                       w_att1, b_att1, w_att2, b_att2, feat);
    hipLaunchKernelGGL(k_gemm1, dim3(NBLK),  dim3(256), 0, stream,
                       feat, w1, b1, y1, part1);
    hipLaunchKernelGGL((k_stats<H1, 400, NBLK>), dim3(H1), dim3(256), 0, stream,
                       part1, g1, be1, sc1, sh1);
    hipLaunchKernelGGL(k_mlp,   dim3(NBLKM), dim3(256), 0, stream,
                       y1, sc1, sh1, a1, w2, b2, y2, part2);
    hipLaunchKernelGGL((k_stats<H2, 160, NBLKM>), dim3(H2), dim3(256), 0, stream,
                       part2, g2, be2, sc2, sh2);
    hipLaunchKernelGGL(k_final, dim3(NBLK),  dim3(256), 0, stream,
                       y2, sc2, sh2, a2, w3, b3, out);
}

// Round 13
// 49.054 us; speedup vs baseline: 3.5176x; 1.0693x over previous
//
#include <hip/hip_runtime.h>
#include <math.h>

namespace {

constexpr int B   = 2048;
constexpr int L   = 200;
constexpr int E   = 96;    // 3 * D_FEAT
constexpr int U   = 64;
constexpr int NA  = 36;    // HID_ATT
constexpr int H1  = 200;
constexpr int H2  = 80;
constexpr int RB  = 8;     // rows per block, gemm1 / final
constexpr int RBM = 4;     // rows per block, mlp
constexpr int NBLK  = B / RB;    // 256
constexpr int NBLKM = B / RBM;   // 512

__device__ __forceinline__ float sigf(float x) {
    return 1.0f / (1.0f + __expf(-x));
}

// DPP partial sums (VALU only, no DS pipe).
template <int CTRL>
__device__ __forceinline__ float dppadd(float x) {
    int v = __builtin_amdgcn_update_dpp(0, __builtin_bit_cast(int, x),
                                        CTRL, 0xf, 0xf, true);
    return x + __builtin_bit_cast(float, v);
}
// sum over each 8-lane group: ^1, ^2, then half-row mirror (i -> 7-i).
__device__ __forceinline__ float grp8_sum(float p) {
    p = dppadd<0xB1>(p);    // quad_perm ^1
    p = dppadd<0x4E>(p);    // quad_perm ^2
    p = dppadd<0x141>(p);   // row_half_mirror: other quad of the 8
    return p;
}
__device__ __forceinline__ float grp32_sum(float p) {
    p = grp8_sum(p);
    p = dppadd<0x140>(p);   // row_mirror: other 8 of the 16
    p += __shfl_xor(p, 16);
    return p;
}

// ---------------------------------------------------------------------------
// K1: one batch row per block. Per-block fold of the linear attention MLP,
// then 32 groups x 8 lanes; lane ln owns features e = 32f + 4ln + {0..3}
// -> each item costs 3 float4 gathers (one full 128B table row per group),
// score reduce = 3 DPP ops. Per wave-iter: 3 VMEM instrs serve 8 items.
// ---------------------------------------------------------------------------
__global__ __launch_bounds__(256) void k_attn(
    const int* __restrict__ user, const int* __restrict__ item,
    const int* __restrict__ rec,
    const float* __restrict__ tu, const float* __restrict__ t1,
    const float* __restrict__ t2, const float* __restrict__ t3,
    const float* __restrict__ w_att1, const float* __restrict__ b_att1,
    const float* __restrict__ w_att2, const float* __restrict__ b_att2,
    float* __restrict__ feat)
{
    __shared__ float s_v[292];
    __shared__ __align__(16) float s_feat[256];
    __shared__ float s_part[32][E];
    __shared__ __align__(16) int4 s_idx4[L];

    const int b = blockIdx.x, t = threadIdx.x;
    const int g = t >> 3, ln = t & 7;

    // ---- fold: s_v[0..95]=v1+v3 | [96..191]=v2-v3 | [192..287]=v4 | [288]=c
    for (int j = t; j < 289; j += 256) {
        float s;
        if (j < 96) {
            s = 0.f;
            #pragma unroll
            for (int k = 0; k < NA; ++k)
                s += w_att2[k] * (w_att1[k * 384 + j] + w_att1[k * 384 + 192 + j]);
        } else if (j < 192) {
            const int e = j - 96; s = 0.f;
            #pragma unroll
            for (int k = 0; k < NA; ++k)
                s += w_att2[k] * (w_att1[k * 384 + 96 + e] - w_att1[k * 384 + 192 + e]);
        } else if (j < 288) {
            const int e = j - 192; s = 0.f;
            #pragma unroll
            for (int k = 0; k < NA; ++k)
                s += w_att2[k] * w_att1[k * 384 + 288 + e];
        } else {
            s = b_att2[0];
            #pragma unroll
            for (int k = 0; k < NA; ++k) s += w_att2[k] * b_att1[k];
        }
        s_v[j] = s;
    }

    // ---- stage idx (padded to int4), q, user emb ---------------------------
    {
        int* si = (int*)s_idx4;
        for (int i = t; i < L * 3; i += 256) {
            const int v = rec[(size_t)b * L * 3 + i];
            si[(i / 3) * 4 + (i % 3)] = v;
        }
    }
    if (t < E) {                          // q = item_emb -> feat[0..95]
        const int f = t >> 5, e = t & 31;
        const float* tab = (f == 0) ? t1 : ((f == 1) ? t2 : t3);
        s_feat[t] = tab[item[b * 3 + f] * 32 + e];
    }
    if (t >= 192) s_feat[t] = tu[(size_t)user[b] * U + (t - 192)];
    __syncthreads();

    // ---- per-lane score weights for features e = 32f + 4ln + c -------------
    float w[12], cb = 0.f;
    #pragma unroll
    for (int f = 0; f < 3; ++f) {
        #pragma unroll
        for (int c = 0; c < 4; ++c) {
            const int e = 32 * f + 4 * ln + c;
            const float q = s_feat[e];
            w[4 * f + c] = s_v[96 + e] + q * s_v[192 + e];
            cb += q * s_v[e];
        }
    }
    cb = grp8_sum(cb) + s_v[288];

    // ---- fused score + browse: items l = g + 32*i, 3 float4 gathers each ---
    float acc[12];
    #pragma unroll
    for (int m = 0; m < 12; ++m) acc[m] = 0.f;
    #pragma unroll
    for (int i = 0; i < 7; ++i) {
        const int l = g + (i << 5);
        if (l < L) {
            const int4 iv = s_idx4[l];
            const float4 u0 = *(const float4*)(t1 + iv.x * 32 + 4 * ln);
            const float4 u1 = *(const float4*)(t2 + iv.y * 32 + 4 * ln);
            const float4 u2 = *(const float4*)(t3 + iv.z * 32 + 4 * ln);
            float p = u0.x * w[0] + u0.y * w[1] + u0.z * w[2]  + u0.w * w[3]
                    + u1.x * w[4] + u1.y * w[5] + u1.z * w[6]  + u1.w * w[7]
                    + u2.x * w[8] + u2.y * w[9] + u2.z * w[10] + u2.w * w[11];
            p = grp8_sum(p);
            const float sc = (iv.x == 0) ? 0.f : (cb + p);
            acc[0] += sc * u0.x; acc[1]  += sc * u0.y;
            acc[2] += sc * u0.z; acc[3]  += sc * u0.w;
            acc[4] += sc * u1.x; acc[5]  += sc * u1.y;
            acc[6] += sc * u1.z; acc[7]  += sc * u1.w;
            acc[8] += sc * u2.x; acc[9]  += sc * u2.y;
            acc[10] += sc * u2.z; acc[11] += sc * u2.w;
        }
    }
    #pragma unroll
    for (int f = 0; f < 3; ++f) {
        #pragma unroll
        for (int c = 0; c < 4; ++c)
            s_part[g][32 * f + 4 * ln + c] = acc[4 * f + c];
    }
    __syncthreads();

    if (t < E) {                          // browse -> feat[96..191]
        float s = 0.f;
        #pragma unroll
        for (int gg = 0; gg < 32; ++gg) s += s_part[gg][t];
        s_feat[96 + t] = s;
    }
    __syncthreads();

    feat[(size_t)b * 256 + t] = s_feat[t];
}

// ---------------------------------------------------------------------------
// K2: y1 = feat @ w1^T + b1 (8 rows/block); per-block column partials to
// part1[blk][0..199]=sum, [200..399]=sumsq. (validated r8/r11/r12)
// ---------------------------------------------------------------------------
__global__ __launch_bounds__(256) void k_gemm1(
    const float* __restrict__ feat,
    const float* __restrict__ w1, const float* __restrict__ b1,
    float* __restrict__ y1, float* __restrict__ part1)
{
    __shared__ __align__(16) float s_f[RB * 256];
    const int t = threadIdx.x, b0 = blockIdx.x * RB;

    const float4* src = (const float4*)(feat + (size_t)b0 * 256);
    float4* dst = (float4*)s_f;
    dst[t] = src[t];
    dst[t + 256] = src[t + 256];
    __syncthreads();

    if (t < H1) {
        const float4* wr = (const float4*)(w1 + t * 256);
        float acc[RB];
        const float bj = b1[t];
        #pragma unroll
        for (int bb = 0; bb < RB; ++bb) acc[bb] = bj;
        #pragma unroll 4
        for (int k = 0; k < 64; ++k) {
            const float4 w = wr[k];
            #pragma unroll
            for (int bb = 0; bb < RB; ++bb) {
                const float4 f = ((const float4*)(s_f + bb * 256))[k];
                acc[bb] += w.x * f.x + w.y * f.y + w.z * f.z + w.w * f.w;
            }
        }
        float s1 = 0.f, s2 = 0.f;
        #pragma unroll
        for (int bb = 0; bb < RB; ++bb) {
            y1[(size_t)(b0 + bb) * H1 + t] = acc[bb];
            s1 += acc[bb]; s2 += acc[bb] * acc[bb];
        }
        part1[(size_t)blockIdx.x * 400 + t]       = s1;
        part1[(size_t)blockIdx.x * 400 + 200 + t] = s2;
    }
}

// ---------------------------------------------------------------------------
// Stats finalize: one block per column; threads sweep NROWS partial rows
// (grid-stride), LDS tree reduce, write sc/sh.
// ---------------------------------------------------------------------------
template <int NCOL, int STRIDE, int NROWS>
__global__ __launch_bounds__(256) void k_stats(
    const float* __restrict__ part, const float* __restrict__ g,
    const float* __restrict__ be,
    float* __restrict__ sc, float* __restrict__ sh)
{
    __shared__ float rs[256], rq[256];
    const int j = blockIdx.x, t = threadIdx.x;
    float s = 0.f, q = 0.f;
    #pragma unroll
    for (int r = t; r < NROWS; r += 256) {
        s += part[(size_t)r * STRIDE + j];
        q += part[(size_t)r * STRIDE + NCOL + j];
    }
    rs[t] = s; rq[t] = q;
    __syncthreads();
    #pragma unroll
    for (int o = 128; o > 0; o >>= 1) {
        if (t < o) { rs[t] += rs[t + o]; rq[t] += rq[t + o]; }
        __syncthreads();
    }
    if (t == 0) {
        const float mean = rs[0] * (1.f / B);
        float var = (rq[0] - (float)B * mean * mean) * (1.f / (B - 1));
        var = fmaxf(var, 0.f);
        const float a = g[j] * rsqrtf(var + 1e-8f);
        sc[j] = a;
        sh[j] = be[j] - mean * a;
    }
}

// ---------------------------------------------------------------------------
// K3: dice(y1) -> y2 = x @ w2^T + b2. RBM=4 rows/block (grid 512 = 2/CU).
// 160 active threads: thread (rr=t/80, j=t%80) computes rows rr and rr+2.
// ---------------------------------------------------------------------------
__global__ __launch_bounds__(256) void k_mlp(
    const float* __restrict__ y1,
    const float* __restrict__ sc1, const float* __restrict__ sh1,
    const float* __restrict__ a1,
    const float* __restrict__ w2, const float* __restrict__ b2,
    float* __restrict__ y2, float* __restrict__ part2)
{
    __shared__ float s_c1[H1], s_h1[H1], s_al[H1];
    __shared__ __align__(16) float s_x[RBM][H1];
    __shared__ float s_p1[2][H2], s_p2[2][H2];
    const int t = threadIdx.x, b0 = blockIdx.x * RBM;

    if (t < H1) { s_c1[t] = sc1[t]; s_h1[t] = sh1[t]; s_al[t] = a1[t]; }
    __syncthreads();

    for (int i = t; i < RBM * H1; i += 256) {
        const int j = i % H1;
        const float xn = y1[(size_t)b0 * H1 + i] * s_c1[j] + s_h1[j];
        const float p  = sigf(xn);
        s_x[i / H1][j] = xn * (p + s_al[j] * (1.f - p));
    }
    __syncthreads();

    const int j = t % H2, rr = t / H2;    // rr 0..1 for t<160
    if (t < 160) {
        const float4* wr = (const float4*)(w2 + j * H1);
        const float bj = b2[j];
        float acc0 = bj, acc1 = bj;       // rows rr, rr+2
        #pragma unroll 2
        for (int k = 0; k < H1 / 4; ++k) {
            const float4 w = wr[k];
            const float4 x0 = ((const float4*)s_x[rr])[k];
            const float4 x1 = ((const float4*)s_x[rr + 2])[k];
            acc0 += w.x * x0.x + w.y * x0.y + w.z * x0.z + w.w * x0.w;
            acc1 += w.x * x1.x + w.y * x1.y + w.z * x1.z + w.w * x1.w;
        }
        y2[(size_t)(b0 + rr) * H2 + j]     = acc0;
        y2[(size_t)(b0 + rr + 2) * H2 + j] = acc1;
        s_p1[rr][j] = acc0 + acc1;
        s_p2[rr][j] = acc0 * acc0 + acc1 * acc1;
    }
    __syncthreads();
    if (t < H2) {
        part2[(size_t)blockIdx.x * 160 + t]      = s_p1[0][t] + s_p1[1][t];
        part2[(size_t)blockIdx.x * 160 + 80 + t] = s_p2[0][t] + s_p2[1][t];
    }
}

// ---------------------------------------------------------------------------
// K4: dice(y2), dot w3, sigmoid. 8 rows/block, 32 lanes per row.
// ---------------------------------------------------------------------------
__global__ __launch_bounds__(256) void k_final(
    const float* __restrict__ y2,
    const float* __restrict__ sc2, const float* __restrict__ sh2,
    const float* __restrict__ a2,
    const float* __restrict__ w3, const float* __restrict__ b3,
    float* __restrict__ out)
{
    __shared__ float s_c[H2], s_s[H2], s_aw[H2], s_w3[H2];
    const int t = threadIdx.x, b0 = blockIdx.x * RB;
    const int g = t >> 5, lane = t & 31;

    if (t < H2) {
        s_c[t] = sc2[t]; s_s[t] = sh2[t];
        s_aw[t] = a2[t]; s_w3[t] = w3[t];
    }
    __syncthreads();

    const int r = b0 + g;
    float acc = 0.f;
    #pragma unroll
    for (int jj = 0; jj < 3; ++jj) {
        const int j = lane + jj * 32;
        if (j < H2) {
            const float xn = y2[(size_t)r * H2 + j] * s_c[j] + s_s[j];
            const float p  = sigf(xn);
            acc += xn * (p + s_aw[j] * (1.f - p)) * s_w3[j];
        }
    }
    acc = grp32_sum(acc);
    if (lane == 0) out[r] = sigf(acc + b3[0]);
}

} // namespace

extern "C" void kernel_launch(void* const* d_in, const int* in_sizes, int n_in,
                              void* d_out, int out_size, void* d_ws, size_t ws_size,
                              hipStream_t stream) {
    const int*   user   = (const int*)d_in[0];
    const int*   item   = (const int*)d_in[1];
    const int*   rec    = (const int*)d_in[2];
    const float* tu     = (const float*)d_in[3];
    const float* t1     = (const float*)d_in[4];
    const float* t2     = (const float*)d_in[5];
    const float* t3     = (const float*)d_in[6];
    const float* w_att1 = (const float*)d_in[7];
    const float* b_att1 = (const float*)d_in[8];
    const float* w_att2 = (const float*)d_in[9];
    const float* b_att2 = (const float*)d_in[10];
    const float* w1     = (const float*)d_in[11];
    const float* b1     = (const float*)d_in[12];
    const float* a1     = (const float*)d_in[13];
    const float* g1     = (const float*)d_in[14];
    const float* be1    = (const float*)d_in[15];
    const float* w2     = (const float*)d_in[16];
    const float* b2     = (const float*)d_in[17];
    const float* a2     = (const float*)d_in[18];
    const float* g2     = (const float*)d_in[19];
    const float* be2    = (const float*)d_in[20];
    const float* w3     = (const float*)d_in[21];
    const float* b3     = (const float*)d_in[22];
    float* out = (float*)d_out;

    float* ws    = (float*)d_ws;
    float* part1 = ws;                            // 256*400
    float* part2 = part1 + (size_t)NBLK * 400;    // 512*160
    float* sc1   = part2 + (size_t)NBLKM * 160;   // 256 (200 used)
    float* sh1   = sc1 + 256;                     // 256
    float* sc2   = sh1 + 256;                     // 128 (80 used)
    float* sh2   = sc2 + 128;                     // 128
    float* feat  = sh2 + 128;                     // B*256
    float* y1    = feat + (size_t)B * 256;        // B*H1
    float* y2    = y1 + (size_t)B * H1;           // B*H2

    hipLaunchKernelGGL(k_attn,  dim3(B),     dim3(256), 0, stream,
                       user, item, rec, tu, t1, t2, t3,
                       w_att1, b_att1, w_att2, b_att2, feat);
    hipLaunchKernelGGL(k_gemm1, dim3(NBLK),  dim3(256), 0, stream,
                       feat, w1, b1, y1, part1);
    hipLaunchKernelGGL((k_stats<H1, 400, NBLK>), dim3(H1), dim3(256), 0, stream,
                       part1, g1, be1, sc1, sh1);
    hipLaunchKernelGGL(k_mlp,   dim3(NBLKM), dim3(256), 0, stream,
                       y1, sc1, sh1, a1, w2, b2, y2, part2);
    hipLaunchKernelGGL((k_stats<H2, 160, NBLKM>), dim3(H2), dim3(256), 0, stream,
                       part2, g2, be2, sc2, sh2);
    hipLaunchKernelGGL(k_final, dim3(NBLK),  dim3(256), 0, stream,
                       y2, sc2, sh2, a2, w3, b3, out);
}